// Round 2
// baseline (523.208 us; speedup 1.0000x reference)
//
#include <hip/hip_runtime.h>
#include <math.h>

// Problem constants (match reference)
constexpr int NB = 8, ND = 8, NH = 512, NW = 1024;
constexpr int NP = NH * NW;        // 524288 pixels / image
constexpr int NG = NP / 4;         // 131072 float4-groups / plane
constexpr int NK = 5;              // labels 1..NK
constexpr int NBLK = 512;          // grid: 2 blocks/CU guaranteed co-resident
constexpr int BPB  = NBLK / NB;    // 64 blocks per image
constexpr int GPB  = NG / BPB;     // 2048 groups per block
constexpr int ITER = GPB / 256;    // 8 iterations per thread
constexpr int NVAL = NK * ND + NK; // 45 reduced values per image

constexpr float DELTA_V = 0.5f;
constexpr float TWO_DELTA_D = 6.0f;  // 2 * delta_d
constexpr float GAMMA = 0.001f;
constexpr int READY_MAGIC = 0x13572468;

#define SCOPE __HIP_MEMORY_SCOPE_AGENT

// ws layout (ints): [0]=bar_cnt [1]=bar_gen [2]=ready [3..15] pad
//                   [16..335]=sums(320f) [336..375]=cnts(40f) [376..415]=vsums(40f)
constexpr int WS_INTS = 416;

__device__ __forceinline__ float wave_sum(float v) {
#pragma unroll
    for (int off = 32; off > 0; off >>= 1) v += __shfl_down(v, off, 64);
    return v;
}

// Generation-based grid barrier; requires all NBLK blocks co-resident
// (guaranteed: 256 thr = 4 waves, launch_bounds(256,2) caps VGPR<=256 ->
//  >=2 blocks/CU -> 512 slots on 256 CUs).
__device__ __forceinline__ void grid_barrier(int* cnt, int* gen) {
    __syncthreads();
    if (threadIdx.x == 0) {
        const int g = __hip_atomic_load(gen, __ATOMIC_ACQUIRE, SCOPE);
        const int t = __hip_atomic_fetch_add(cnt, 1, __ATOMIC_ACQ_REL, SCOPE);
        if (t == NBLK - 1) {
            __hip_atomic_store(cnt, 0, __ATOMIC_RELAXED, SCOPE);
            __hip_atomic_fetch_add(gen, 1, __ATOMIC_ACQ_REL, SCOPE);
        } else {
            while (__hip_atomic_load(gen, __ATOMIC_ACQUIRE, SCOPE) == g)
                __builtin_amdgcn_s_sleep(2);
        }
    }
    __syncthreads();
}

__global__ __launch_bounds__(256, 2) void disc_fused(
    const float* __restrict__ emb, const int* __restrict__ mask,
    int* __restrict__ wsi, float* __restrict__ out)
{
    float* const sums    = (float*)(wsi + 16);      // [NB][NK][ND]
    float* const cnts    = sums + NB * NK * ND;     // [NB][NK]
    float* const vsums   = cnts + NB * NK;          // [NB][NK]
    int* const   bar_cnt = wsi + 0;
    int* const   bar_gen = wsi + 1;
    int* const   ready   = wsi + 2;

    const int b   = blockIdx.x / BPB;
    const int blk = blockIdx.x % BPB;
    const long base = (long)blk * GPB;
    const float4* emb4 = (const float4*)emb + (long)b * ND * NG;
    const int4*   m4p  = (const int4*)mask + (long)b * NG;

    // Block 0 zeroes the poisoned (0xAA) reduction workspace and publishes it.
    if (blockIdx.x == 0) {
        for (int i = threadIdx.x; i < WS_INTS; i += 256)
            __hip_atomic_store(wsi + i, 0, __ATOMIC_RELAXED, SCOPE);
        __syncthreads();
        if (threadIdx.x == 0)
            __hip_atomic_store(ready, READY_MAGIC, __ATOMIC_RELEASE, SCOPE);
    }

    // ---------------- Phase A: per-(b,k) sums + counts ----------------
    float acc[NK][ND], cnt[NK];
#pragma unroll
    for (int k = 0; k < NK; ++k) {
        cnt[k] = 0.f;
#pragma unroll
        for (int d = 0; d < ND; ++d) acc[k][d] = 0.f;
    }

#pragma unroll
    for (int i = 0; i < ITER; ++i) {
        const long g = base + threadIdx.x + i * 256;
        const int4 m = m4p[g];
        float4 e[ND];
#pragma unroll
        for (int d = 0; d < ND; ++d) e[d] = emb4[(long)d * NG + g];
        const int labs[4] = {m.x, m.y, m.z, m.w};
#pragma unroll
        for (int j = 0; j < 4; ++j) {
            const int lab = labs[j];
#pragma unroll
            for (int k = 0; k < NK; ++k) {
                const bool sel = (lab == k + 1);
                cnt[k] += sel ? 1.f : 0.f;
#pragma unroll
                for (int d = 0; d < ND; ++d)
                    acc[k][d] += sel ? ((const float*)&e[d])[j] : 0.f;
            }
        }
    }

    __shared__ float part[4][NVAL];
    const int lane = threadIdx.x & 63;
    const int wave = threadIdx.x >> 6;
#pragma unroll
    for (int k = 0; k < NK; ++k) {
#pragma unroll
        for (int d = 0; d < ND; ++d) {
            const float r = wave_sum(acc[k][d]);
            if (lane == 0) part[wave][k * ND + d] = r;
        }
        const float rc = wave_sum(cnt[k]);
        if (lane == 0) part[wave][NK * ND + k] = rc;
    }
    // Gate: ensure ws is zeroed before any atomicAdd (no wait in practice —
    // block 0 zeroes in <1us while everyone streams 256KB).
    if (threadIdx.x == 0 && blockIdx.x != 0) {
        while (__hip_atomic_load(ready, __ATOMIC_ACQUIRE, SCOPE) != READY_MAGIC)
            __builtin_amdgcn_s_sleep(2);
    }
    __syncthreads();
    if (threadIdx.x < NVAL) {
        const float s = part[0][threadIdx.x] + part[1][threadIdx.x] +
                        part[2][threadIdx.x] + part[3][threadIdx.x];
        float* dst = (threadIdx.x < NK * ND)
                         ? &sums[b * NK * ND + threadIdx.x]
                         : &cnts[b * NK + (threadIdx.x - NK * ND)];
        atomicAdd(dst, s);
    }
    grid_barrier(bar_cnt, bar_gen);

    // ---------------- Phase B: variance hinge sums ----------------
    // Stage the 45 reduced values through LDS with device-scope atomic loads
    // (cross-XCD safe: plain loads could hit a stale local-L2 line).
    __shared__ float csh[NVAL];
    if (threadIdx.x < NVAL) {
        const float* src = (threadIdx.x < NK * ND)
                               ? &sums[b * NK * ND + threadIdx.x]
                               : &cnts[b * NK + (threadIdx.x - NK * ND)];
        csh[threadIdx.x] = __hip_atomic_load(src, __ATOMIC_RELAXED, SCOPE);
    }
    __syncthreads();
    float c[NK][ND];
#pragma unroll
    for (int k = 0; k < NK; ++k) {
        const float inv = 1.f / fmaxf(csh[NK * ND + k], 1.f);
#pragma unroll
        for (int d = 0; d < ND; ++d) c[k][d] = csh[k * ND + d] * inv;
    }

    float vacc[NK] = {0.f, 0.f, 0.f, 0.f, 0.f};
#pragma unroll
    for (int i = 0; i < ITER; ++i) {
        const long g = base + threadIdx.x + i * 256;
        const int4 m = m4p[g];
        float4 e[ND];
#pragma unroll
        for (int d = 0; d < ND; ++d) e[d] = emb4[(long)d * NG + g];
        const int labs[4] = {m.x, m.y, m.z, m.w};
#pragma unroll
        for (int j = 0; j < 4; ++j) {
            const int lab = labs[j];
            float dsq = 0.f;
#pragma unroll
            for (int d = 0; d < ND; ++d) {
                float cd = c[0][d];
                cd = (lab == 2) ? c[1][d] : cd;
                cd = (lab == 3) ? c[2][d] : cd;
                cd = (lab == 4) ? c[3][d] : cd;
                cd = (lab == 5) ? c[4][d] : cd;
                const float diff = ((const float*)&e[d])[j] - cd;
                dsq = fmaf(diff, diff, dsq);
            }
            const float dist = sqrtf(dsq);
            const float hv = fmaxf(dist - DELTA_V, 0.f);
            const float val = hv * hv;
#pragma unroll
            for (int k = 0; k < NK; ++k)
                vacc[k] += (lab == k + 1) ? val : 0.f;
        }
    }
#pragma unroll
    for (int k = 0; k < NK; ++k) {
        const float r = wave_sum(vacc[k]);
        if (lane == 0) part[wave][k] = r;
    }
    __syncthreads();
    if (threadIdx.x < NK) {
        const float s = part[0][threadIdx.x] + part[1][threadIdx.x] +
                        part[2][threadIdx.x] + part[3][threadIdx.x];
        atomicAdd(&vsums[b * NK + threadIdx.x], s);
    }
    grid_barrier(bar_cnt, bar_gen);

    // ---------------- Phase C: tiny O(B*K^2) epilogue ----------------
    if (blockIdx.x == 0 && threadIdx.x == 0) {
        float tv = 0.f, td = 0.f, tr = 0.f, hs = 0.f;
        for (int bb = 0; bb < NB; ++bb) {
            float cc[NK], CC[NK][ND];
            bool pres[NK];
            float N = 0.f;
            for (int k = 0; k < NK; ++k) {
                cc[k] = __hip_atomic_load(&cnts[bb * NK + k], __ATOMIC_RELAXED, SCOPE);
                pres[k] = cc[k] > 0.f;
                if (pres[k]) N += 1.f;
                const float inv = 1.f / fmaxf(cc[k], 1.f);
                for (int d = 0; d < ND; ++d)
                    CC[k][d] = __hip_atomic_load(&sums[bb * NK * ND + k * ND + d],
                                                 __ATOMIC_RELAXED, SCOPE) * inv;
            }
            float lv = 0.f;
            for (int k = 0; k < NK; ++k)
                if (pres[k])
                    lv += __hip_atomic_load(&vsums[bb * NK + k], __ATOMIC_RELAXED, SCOPE)
                          / fmaxf(cc[k], 1.f);
            lv /= fmaxf(N, 1.f);

            float ld = 0.f;
            for (int i2 = 0; i2 < NK; ++i2)
                for (int j2 = i2 + 1; j2 < NK; ++j2)
                    if (pres[i2] && pres[j2]) {
                        float dsq = 0.f;
                        for (int d = 0; d < ND; ++d) {
                            const float df = CC[i2][d] - CC[j2][d];
                            dsq = fmaf(df, df, dsq);
                        }
                        const float t = fmaxf(TWO_DELTA_D - sqrtf(dsq), 0.f);
                        ld += t * t;
                    }
            const float npairs = N * (N - 1.f) * 0.5f;
            ld /= (N > 1.f) ? npairs : 1.f;

            float lr = 0.f;
            for (int k = 0; k < NK; ++k)
                if (pres[k]) {
                    float sq = 0.f;
                    for (int d = 0; d < ND; ++d) sq = fmaf(CC[k][d], CC[k][d], sq);
                    lr += sqrtf(sq);
                }
            lr /= fmaxf(N, 1.f);

            if (N > 0.f) { tv += lv; td += ld; tr += lr; hs += 1.f; }
        }
        const float den = fmaxf(hs, 1.f);
        tv /= den; td /= den; tr /= den;
        out[0] = tv + td + GAMMA * tr;
        out[1] = tv;
        out[2] = td;
        out[3] = tr;
    }
}

extern "C" void kernel_launch(void* const* d_in, const int* in_sizes, int n_in,
                              void* d_out, int out_size, void* d_ws, size_t ws_size,
                              hipStream_t stream) {
    const float* emb  = (const float*)d_in[0];
    const int*   mask = (const int*)d_in[1];
    disc_fused<<<dim3(NBLK), dim3(256), 0, stream>>>(emb, mask, (int*)d_ws, (float*)d_out);
}

// Round 3
// 335.152 us; speedup vs baseline: 1.5611x; 1.5611x over previous
//
#include <hip/hip_runtime.h>
#include <math.h>

// Problem constants
constexpr int NB = 8, ND = 8, NP = 512 * 1024, NG = NP / 4, NK = 5;
constexpr int BPB  = 128;           // blocks per image (both kernels)
constexpr int NBLK = NB * BPB;      // 1024 blocks
constexpr int GPB  = NG / BPB;      // 1024 float4-groups per block
constexpr int ITER = GPB / 256;     // 4 iterations per thread
constexpr int PSTR = 48;            // partial-slot stride (40 sums + 5 cnts + pad)

constexpr float DELTA_V = 0.5f, TWO_DELTA_D = 6.0f, GAMMA = 0.001f;
#define SCOPE __HIP_MEMORY_SCOPE_AGENT

// ws float layout:
//   [0]                       done counter (int)
//   [64  .. 64+8*48)          totals per image (released by blk==0 of each image)
//   [512 .. 512+NBLK*8)       per-block vsum partials (released)
//   [16384 .. 16384+NBLK*48)  K1 per-block partials (plain; kernel boundary syncs)
constexpr int OFF_TOT = 64, OFF_VP = 512, OFF_P1 = 16384;

__device__ __forceinline__ float wave_sum(float v) {
#pragma unroll
    for (int off = 32; off > 0; off >>= 1) v += __shfl_down(v, off, 64);
    return v;
}

// ---------------- K1: per-block (k,d)-sums + counts -> partials ----------------
__global__ __launch_bounds__(256, 4) void k1_partials(
    const float* __restrict__ emb, const int* __restrict__ mask,
    float* __restrict__ ws)
{
    const int b   = blockIdx.x / BPB;
    const int blk = blockIdx.x % BPB;
    const float4* emb4 = (const float4*)emb + (size_t)b * ND * NG;
    const int4*   m4   = (const int4*)mask + (size_t)b * NG;
    const int base = blk * GPB;

    float acc[NK][ND], cnt[NK];
#pragma unroll
    for (int k = 0; k < NK; ++k) {
        cnt[k] = 0.f;
#pragma unroll
        for (int d = 0; d < ND; ++d) acc[k][d] = 0.f;
    }

#pragma unroll 1
    for (int i = 0; i < ITER; ++i) {
        const int g = base + i * 256 + threadIdx.x;
        const int4 m = m4[g];
        float4 e[ND];
#pragma unroll
        for (int d = 0; d < ND; ++d) e[d] = emb4[(size_t)d * NG + g];
        const int labs[4] = {m.x, m.y, m.z, m.w};
#pragma unroll
        for (int j = 0; j < 4; ++j) {
            const int lab = labs[j];
#pragma unroll
            for (int k = 0; k < NK; ++k) {
                const bool sel = (lab == k + 1);
                cnt[k] += sel ? 1.f : 0.f;
#pragma unroll
                for (int d = 0; d < ND; ++d)
                    acc[k][d] += sel ? ((const float*)&e[d])[j] : 0.f;
            }
        }
    }

    __shared__ float part[4][PSTR];
    const int lane = threadIdx.x & 63, wave = threadIdx.x >> 6;
#pragma unroll
    for (int k = 0; k < NK; ++k) {
#pragma unroll
        for (int d = 0; d < ND; ++d) {
            const float r = wave_sum(acc[k][d]);
            if (lane == 0) part[wave][k * ND + d] = r;
        }
        const float rc = wave_sum(cnt[k]);
        if (lane == 0) part[wave][NK * ND + k] = rc;
    }
    __syncthreads();
    if (threadIdx.x < 45) {
        const float s = part[0][threadIdx.x] + part[1][threadIdx.x] +
                        part[2][threadIdx.x] + part[3][threadIdx.x];
        ws[OFF_P1 + (size_t)blockIdx.x * PSTR + threadIdx.x] = s;
    }
    if (blockIdx.x == 0 && threadIdx.x == 0)
        ((int*)ws)[0] = 0;   // done-counter for K2; kernel boundary publishes
}

// ---------------- K2: hinge pass + last-block epilogue ----------------
__global__ __launch_bounds__(256, 4) void k2_hinge(
    const float* __restrict__ emb, const int* __restrict__ mask,
    float* __restrict__ ws, float* __restrict__ out)
{
    const int b   = blockIdx.x / BPB;
    const int blk = blockIdx.x % BPB;

    __shared__ float red1[45][4];
    __shared__ float csh[PSTR];
    __shared__ float part[4][8];
    __shared__ float vred[NB][NK][4];
    __shared__ float tsh[NB][PSTR];
    __shared__ bool  amlast;

    // Preamble: reduce this image's 128 K1 partials (plain loads; kernel
    // boundary made K1's stores visible).
    if (threadIdx.x < 180) {
        const int v = threadIdx.x >> 2, q = threadIdx.x & 3;
        const float* p = ws + OFF_P1 + ((size_t)b * BPB + q * 32) * PSTR + v;
        float s = 0.f;
#pragma unroll 8
        for (int i = 0; i < 32; ++i) s += p[(size_t)i * PSTR];
        red1[v][q] = s;
    }
    __syncthreads();
    if (threadIdx.x < 45) {
        const float s = red1[threadIdx.x][0] + red1[threadIdx.x][1] +
                        red1[threadIdx.x][2] + red1[threadIdx.x][3];
        csh[threadIdx.x] = s;
        if (blk == 0)   // publish totals for the last-block epilogue
            __hip_atomic_store(&ws[OFF_TOT + b * PSTR + threadIdx.x], s,
                               __ATOMIC_RELEASE, SCOPE);
    }
    __syncthreads();

    float c[NK][ND];
#pragma unroll
    for (int k = 0; k < NK; ++k) {
        const float inv = 1.f / fmaxf(csh[NK * ND + k], 1.f);
#pragma unroll
        for (int d = 0; d < ND; ++d) c[k][d] = csh[k * ND + d] * inv;
    }

    const float4* emb4 = (const float4*)emb + (size_t)b * ND * NG;
    const int4*   m4   = (const int4*)mask + (size_t)b * NG;
    const int base = blk * GPB;

    float vacc[NK] = {0.f, 0.f, 0.f, 0.f, 0.f};
#pragma unroll 1
    for (int i = 0; i < ITER; ++i) {
        const int g = base + i * 256 + threadIdx.x;
        const int4 m = m4[g];
        float4 e[ND];
#pragma unroll
        for (int d = 0; d < ND; ++d) e[d] = emb4[(size_t)d * NG + g];
        const int labs[4] = {m.x, m.y, m.z, m.w};
#pragma unroll
        for (int j = 0; j < 4; ++j) {
            const int lab = labs[j];
            float dsq = 0.f;
#pragma unroll
            for (int d = 0; d < ND; ++d) {
                float cd = c[0][d];
                cd = (lab == 2) ? c[1][d] : cd;
                cd = (lab == 3) ? c[2][d] : cd;
                cd = (lab == 4) ? c[3][d] : cd;
                cd = (lab == 5) ? c[4][d] : cd;
                const float diff = ((const float*)&e[d])[j] - cd;
                dsq = fmaf(diff, diff, dsq);
            }
            const float hv = fmaxf(sqrtf(dsq) - DELTA_V, 0.f);
            const float val = hv * hv;
#pragma unroll
            for (int k = 0; k < NK; ++k)
                vacc[k] += (lab == k + 1) ? val : 0.f;
        }
    }

    const int lane = threadIdx.x & 63, wave = threadIdx.x >> 6;
#pragma unroll
    for (int k = 0; k < NK; ++k) {
        const float r = wave_sum(vacc[k]);
        if (lane == 0) part[wave][k] = r;
    }
    __syncthreads();
    if (threadIdx.x < NK) {
        const float s = part[0][threadIdx.x] + part[1][threadIdx.x] +
                        part[2][threadIdx.x] + part[3][threadIdx.x];
        __hip_atomic_store(&ws[OFF_VP + (size_t)blockIdx.x * 8 + threadIdx.x], s,
                           __ATOMIC_RELEASE, SCOPE);
    }
    __syncthreads();
    if (threadIdx.x == 0) {
        const int old = __hip_atomic_fetch_add((int*)ws, 1, __ATOMIC_ACQ_REL, SCOPE);
        amlast = (old == NBLK - 1);
    }
    __syncthreads();
    if (!amlast) return;

    // ---- last block: gather per-image vsums + totals, compute the loss ----
    if (threadIdx.x < 160) {
        const int bb = threadIdx.x / 20, r = threadIdx.x % 20;
        const int k = r >> 2, q = r & 3;
        float s = 0.f;
#pragma unroll 8
        for (int i = 0; i < 32; ++i)
            s += __hip_atomic_load(&ws[OFF_VP + (size_t)(bb * BPB + q * 32 + i) * 8 + k],
                                   __ATOMIC_RELAXED, SCOPE);
        vred[bb][k][q] = s;
    }
    for (int t = threadIdx.x; t < NB * PSTR; t += 256) {
        const int bb = t / PSTR, j = t % PSTR;
        tsh[bb][j] = __hip_atomic_load(&ws[OFF_TOT + bb * PSTR + j],
                                       __ATOMIC_RELAXED, SCOPE);
    }
    __syncthreads();
    if (threadIdx.x == 0) {
        float tv = 0.f, td = 0.f, tr = 0.f, hs = 0.f;
        for (int bb = 0; bb < NB; ++bb) {
            float cc[NK], CC[NK][ND];
            bool pres[NK];
            float N = 0.f;
            for (int k = 0; k < NK; ++k) {
                cc[k] = tsh[bb][NK * ND + k];
                pres[k] = cc[k] > 0.f;
                if (pres[k]) N += 1.f;
                const float inv = 1.f / fmaxf(cc[k], 1.f);
                for (int d = 0; d < ND; ++d)
                    CC[k][d] = tsh[bb][k * ND + d] * inv;
            }
            float lv = 0.f;
            for (int k = 0; k < NK; ++k)
                if (pres[k]) {
                    const float vs = vred[bb][k][0] + vred[bb][k][1] +
                                     vred[bb][k][2] + vred[bb][k][3];
                    lv += vs / fmaxf(cc[k], 1.f);
                }
            lv /= fmaxf(N, 1.f);

            float ld = 0.f;
            for (int i2 = 0; i2 < NK; ++i2)
                for (int j2 = i2 + 1; j2 < NK; ++j2)
                    if (pres[i2] && pres[j2]) {
                        float dsq = 0.f;
                        for (int d = 0; d < ND; ++d) {
                            const float df = CC[i2][d] - CC[j2][d];
                            dsq = fmaf(df, df, dsq);
                        }
                        const float t = fmaxf(TWO_DELTA_D - sqrtf(dsq), 0.f);
                        ld += t * t;
                    }
            const float npairs = N * (N - 1.f) * 0.5f;
            ld /= (N > 1.f) ? npairs : 1.f;

            float lr = 0.f;
            for (int k = 0; k < NK; ++k)
                if (pres[k]) {
                    float sq = 0.f;
                    for (int d = 0; d < ND; ++d) sq = fmaf(CC[k][d], CC[k][d], sq);
                    lr += sqrtf(sq);
                }
            lr /= fmaxf(N, 1.f);

            if (N > 0.f) { tv += lv; td += ld; tr += lr; hs += 1.f; }
        }
        const float den = fmaxf(hs, 1.f);
        tv /= den; td /= den; tr /= den;
        out[0] = tv + td + GAMMA * tr;
        out[1] = tv;
        out[2] = td;
        out[3] = tr;
    }
}

extern "C" void kernel_launch(void* const* d_in, const int* in_sizes, int n_in,
                              void* d_out, int out_size, void* d_ws, size_t ws_size,
                              hipStream_t stream) {
    const float* emb  = (const float*)d_in[0];
    const int*   mask = (const int*)d_in[1];
    float* ws = (float*)d_ws;
    k1_partials<<<dim3(NBLK), dim3(256), 0, stream>>>(emb, mask, ws);
    k2_hinge<<<dim3(NBLK), dim3(256), 0, stream>>>(emb, mask, ws, (float*)d_out);
}

// Round 4
// 292.042 us; speedup vs baseline: 1.7916x; 1.1476x over previous
//
#include <hip/hip_runtime.h>
#include <math.h>

// Problem constants
constexpr int NB = 8, ND = 8, NP = 512 * 1024, NG = NP / 4, NK = 5;
constexpr int BPB  = 128;           // blocks per image (both kernels)
constexpr int NBLK = NB * BPB;      // 1024 blocks
constexpr int GPB  = NG / BPB;      // 1024 float4-groups per block
constexpr int ITER = GPB / 256;     // 4 iterations per thread
constexpr int PSTR = 48;            // 40 sums + 5 cnts + pad

constexpr float DELTA_V = 0.5f, TWO_DELTA_D = 6.0f, GAMMA = 0.001f;
#define SCOPE __HIP_MEMORY_SCOPE_AGENT

// ws float layout:
//   [0]                        done counter (int)
//   [64  .. 64+8*48)           totals per image (released by blk==0 of each image)
//   [512 .. 512+NBLK*8)        per-block vsum partials (released)
//   [16384 .. 16384+45*NBLK)   K1 partials, TRANSPOSED [45][NBLK] (plain stores;
//                              kernel boundary syncs)
constexpr int OFF_TOT = 64, OFF_VP = 512, OFF_P1 = 16384;

__device__ __forceinline__ float wave_sum(float v) {
#pragma unroll
    for (int off = 32; off > 0; off >>= 1) v += __shfl_down(v, off, 64);
    return v;
}

// ---------------- K1: per-block (k,d)-sums + counts -> partials ----------------
// NOTE: no min-waves hint — R3's __launch_bounds__(256,4) forced VGPR=32,
// spilling the 45 accumulators to scratch (41 MB WRITE_SIZE, 1.5 TB/s).
__global__ __launch_bounds__(256) void k1_partials(
    const float* __restrict__ emb, const int* __restrict__ mask,
    float* __restrict__ ws)
{
    const int b   = blockIdx.x / BPB;
    const int blk = blockIdx.x % BPB;
    const float4* emb4 = (const float4*)emb + (size_t)b * ND * NG;
    const int4*   m4   = (const int4*)mask + (size_t)b * NG;
    const int base = blk * GPB;

    float acc[NK][ND], cnt[NK];
#pragma unroll
    for (int k = 0; k < NK; ++k) {
        cnt[k] = 0.f;
#pragma unroll
        for (int d = 0; d < ND; ++d) acc[k][d] = 0.f;
    }

#pragma unroll 1
    for (int i = 0; i < ITER; ++i) {
        const int g = base + i * 256 + threadIdx.x;
        const int4 m = m4[g];
        float4 e[ND];
#pragma unroll
        for (int d = 0; d < ND; ++d) e[d] = emb4[(size_t)d * NG + g];
        const int labs[4] = {m.x, m.y, m.z, m.w};
#pragma unroll
        for (int j = 0; j < 4; ++j) {
            const int lab = labs[j];
#pragma unroll
            for (int k = 0; k < NK; ++k) {
                const bool sel = (lab == k + 1);
                cnt[k] += sel ? 1.f : 0.f;
#pragma unroll
                for (int d = 0; d < ND; ++d)
                    acc[k][d] += sel ? ((const float*)&e[d])[j] : 0.f;
            }
        }
    }

    __shared__ float part[4][PSTR];
    const int lane = threadIdx.x & 63, wave = threadIdx.x >> 6;
#pragma unroll
    for (int k = 0; k < NK; ++k) {
#pragma unroll
        for (int d = 0; d < ND; ++d) {
            const float r = wave_sum(acc[k][d]);
            if (lane == 0) part[wave][k * ND + d] = r;
        }
        const float rc = wave_sum(cnt[k]);
        if (lane == 0) part[wave][NK * ND + k] = rc;
    }
    __syncthreads();
    if (threadIdx.x < 45) {
        const float s = part[0][threadIdx.x] + part[1][threadIdx.x] +
                        part[2][threadIdx.x] + part[3][threadIdx.x];
        // transposed: value-major so K2's reduction is coalesced
        ws[OFF_P1 + (size_t)threadIdx.x * NBLK + blockIdx.x] = s;
    }
    if (blockIdx.x == 0 && threadIdx.x == 0)
        ((int*)ws)[0] = 0;   // done-counter for K2; kernel boundary publishes
}

// ---------------- K2: hinge pass + last-block epilogue ----------------
__global__ __launch_bounds__(256) void k2_hinge(
    const float* __restrict__ emb, const int* __restrict__ mask,
    float* __restrict__ ws, float* __restrict__ out)
{
    const int b   = blockIdx.x / BPB;
    const int blk = blockIdx.x % BPB;

    __shared__ float red1[45][4];
    __shared__ float csh[PSTR];
    __shared__ float cLDS[6][ND];    // row 0 = zeros (background), rows 1..5 = centers
    __shared__ float part[4][8];
    __shared__ float vred[NB][NK][4];
    __shared__ float tsh[NB][PSTR];
    __shared__ bool  amlast;

    // Preamble: reduce this image's 128 K1 partials (coalesced: [45][NBLK]).
    if (threadIdx.x < 180) {
        const int v = threadIdx.x >> 2, q = threadIdx.x & 3;
        const float* p = ws + OFF_P1 + (size_t)v * NBLK + b * BPB + q * 32;
        float s = 0.f;
#pragma unroll
        for (int i = 0; i < 32; ++i) s += p[i];
        red1[v][q] = s;
    }
    __syncthreads();
    if (threadIdx.x < 45) {
        const float s = red1[threadIdx.x][0] + red1[threadIdx.x][1] +
                        red1[threadIdx.x][2] + red1[threadIdx.x][3];
        csh[threadIdx.x] = s;
        if (blk == 0)   // publish totals for the last-block epilogue
            __hip_atomic_store(&ws[OFF_TOT + b * PSTR + threadIdx.x], s,
                               __ATOMIC_RELEASE, SCOPE);
    }
    __syncthreads();
    // Centers into LDS, indexed by raw label (0 -> zeros; no accumulate happens
    // for background so the distance result is discarded anyway).
    if (threadIdx.x < 48) {
        const int row = threadIdx.x >> 3, d = threadIdx.x & 7;
        float v = 0.f;
        if (row > 0)
            v = csh[(row - 1) * ND + d] / fmaxf(csh[NK * ND + (row - 1)], 1.f);
        cLDS[row][d] = v;
    }
    __syncthreads();

    const float4* emb4 = (const float4*)emb + (size_t)b * ND * NG;
    const int4*   m4   = (const int4*)mask + (size_t)b * NG;
    const int base = blk * GPB;

    float vacc[NK] = {0.f, 0.f, 0.f, 0.f, 0.f};
#pragma unroll 1
    for (int i = 0; i < ITER; ++i) {
        const int g = base + i * 256 + threadIdx.x;
        const int4 m = m4[g];
        float4 e[ND];
#pragma unroll
        for (int d = 0; d < ND; ++d) e[d] = emb4[(size_t)d * NG + g];
        const int labs[4] = {m.x, m.y, m.z, m.w};
#pragma unroll
        for (int j = 0; j < 4; ++j) {
            const int lab = labs[j];
            const float4* crow = (const float4*)&cLDS[lab][0];
            const float4 c0 = crow[0], c1 = crow[1];
            const float cd[8] = {c0.x, c0.y, c0.z, c0.w, c1.x, c1.y, c1.z, c1.w};
            float dsq = 0.f;
#pragma unroll
            for (int d = 0; d < ND; ++d) {
                const float diff = ((const float*)&e[d])[j] - cd[d];
                dsq = fmaf(diff, diff, dsq);
            }
            const float hv = fmaxf(sqrtf(dsq) - DELTA_V, 0.f);
            const float val = hv * hv;
#pragma unroll
            for (int k = 0; k < NK; ++k)
                vacc[k] += (lab == k + 1) ? val : 0.f;
        }
    }

    const int lane = threadIdx.x & 63, wave = threadIdx.x >> 6;
#pragma unroll
    for (int k = 0; k < NK; ++k) {
        const float r = wave_sum(vacc[k]);
        if (lane == 0) part[wave][k] = r;
    }
    __syncthreads();
    if (threadIdx.x < NK) {
        const float s = part[0][threadIdx.x] + part[1][threadIdx.x] +
                        part[2][threadIdx.x] + part[3][threadIdx.x];
        __hip_atomic_store(&ws[OFF_VP + (size_t)blockIdx.x * 8 + threadIdx.x], s,
                           __ATOMIC_RELEASE, SCOPE);
    }
    __syncthreads();
    if (threadIdx.x == 0) {
        const int old = __hip_atomic_fetch_add((int*)ws, 1, __ATOMIC_ACQ_REL, SCOPE);
        amlast = (old == NBLK - 1);
    }
    __syncthreads();
    if (!amlast) return;

    // ---- last block: gather per-image vsums + totals, compute the loss ----
    if (threadIdx.x < 160) {
        const int bb = threadIdx.x / 20, r = threadIdx.x % 20;
        const int k = r >> 2, q = r & 3;
        float s = 0.f;
#pragma unroll
        for (int i = 0; i < 32; ++i)
            s += __hip_atomic_load(&ws[OFF_VP + (size_t)(bb * BPB + q * 32 + i) * 8 + k],
                                   __ATOMIC_RELAXED, SCOPE);
        vred[bb][k][q] = s;
    }
    for (int t = threadIdx.x; t < NB * PSTR; t += 256) {
        const int bb = t / PSTR, j = t % PSTR;
        tsh[bb][j] = __hip_atomic_load(&ws[OFF_TOT + bb * PSTR + j],
                                       __ATOMIC_RELAXED, SCOPE);
    }
    __syncthreads();
    if (threadIdx.x == 0) {
        float tv = 0.f, td = 0.f, tr = 0.f, hs = 0.f;
        for (int bb = 0; bb < NB; ++bb) {
            float cc[NK], CC[NK][ND];
            bool pres[NK];
            float N = 0.f;
            for (int k = 0; k < NK; ++k) {
                cc[k] = tsh[bb][NK * ND + k];
                pres[k] = cc[k] > 0.f;
                if (pres[k]) N += 1.f;
                const float inv = 1.f / fmaxf(cc[k], 1.f);
                for (int d = 0; d < ND; ++d)
                    CC[k][d] = tsh[bb][k * ND + d] * inv;
            }
            float lv = 0.f;
            for (int k = 0; k < NK; ++k)
                if (pres[k]) {
                    const float vs = vred[bb][k][0] + vred[bb][k][1] +
                                     vred[bb][k][2] + vred[bb][k][3];
                    lv += vs / fmaxf(cc[k], 1.f);
                }
            lv /= fmaxf(N, 1.f);

            float ld = 0.f;
            for (int i2 = 0; i2 < NK; ++i2)
                for (int j2 = i2 + 1; j2 < NK; ++j2)
                    if (pres[i2] && pres[j2]) {
                        float dsq = 0.f;
                        for (int d = 0; d < ND; ++d) {
                            const float df = CC[i2][d] - CC[j2][d];
                            dsq = fmaf(df, df, dsq);
                        }
                        const float t = fmaxf(TWO_DELTA_D - sqrtf(dsq), 0.f);
                        ld += t * t;
                    }
            const float npairs = N * (N - 1.f) * 0.5f;
            ld /= (N > 1.f) ? npairs : 1.f;

            float lr = 0.f;
            for (int k = 0; k < NK; ++k)
                if (pres[k]) {
                    float sq = 0.f;
                    for (int d = 0; d < ND; ++d) sq = fmaf(CC[k][d], CC[k][d], sq);
                    lr += sqrtf(sq);
                }
            lr /= fmaxf(N, 1.f);

            if (N > 0.f) { tv += lv; td += ld; tr += lr; hs += 1.f; }
        }
        const float den = fmaxf(hs, 1.f);
        tv /= den; td /= den; tr /= den;
        out[0] = tv + td + GAMMA * tr;
        out[1] = tv;
        out[2] = td;
        out[3] = tr;
    }
}

extern "C" void kernel_launch(void* const* d_in, const int* in_sizes, int n_in,
                              void* d_out, int out_size, void* d_ws, size_t ws_size,
                              hipStream_t stream) {
    const float* emb  = (const float*)d_in[0];
    const int*   mask = (const int*)d_in[1];
    float* ws = (float*)d_ws;
    k1_partials<<<dim3(NBLK), dim3(256), 0, stream>>>(emb, mask, ws);
    k2_hinge<<<dim3(NBLK), dim3(256), 0, stream>>>(emb, mask, ws, (float*)d_out);
}